// Round 1
// 5988.084 us; speedup vs baseline: 1.7546x; 1.7546x over previous
//
#include <hip/hip_runtime.h>

typedef _Float16 f16;
typedef _Float16 f16x4 __attribute__((ext_vector_type(4)));
typedef _Float16 f16x8 __attribute__((ext_vector_type(8)));
typedef float    f32x4 __attribute__((ext_vector_type(4)));

#define MFMA16(a, b, c) __builtin_amdgcn_mfma_f32_16x16x32_f16(a, b, c, 0, 0, 0)

// Problem constants
static constexpr int kS  = 512;
static constexpr int kB  = 64;
static constexpr int kDI = 512;
static constexpr int kDL = 1024;
static constexpr int kV  = 50257;

// ---------------------------------------------------------------------------
// Cross-XCD exchange primitives (LLC-coherent, NO cache-maintenance fences).
// Stores: write-through to LLC (sc0 sc1). Loads: agent-scope relaxed atomics
// (bypass stale L1/L2, LLC-served). MALL is memory-side => always coherent.
//
// R0 (this session): exchange buffers are FRAGMENT-ORDERED + SPLIT-PLANE so
// the consumer's agent-scope loads are fully coalesced:
//   layout (8B words): [frag = mt*32+ks][plane(2)][lane(64)]
//   word(frag,plane,lane) slot i(0..3) = h[b = mt*16 + (lane&15)]
//                                         [k = ks*32 + (lane>>4)*8 + plane*4 + i]
// Consumer fragment (ks,mt) = two coalesced 512B wave-loads (8 fabric lines
// vs 32 for the old row-major layout => 4096 -> 512 transactions/block/phase).
union U128 { unsigned long long q[2]; f16x8 v; };

static __device__ __forceinline__ void store_llc_f16(f16* p, f16 v) {
  unsigned v32 = (unsigned)__builtin_bit_cast(unsigned short, v);
  asm volatile("global_store_short %0, %1, off sc0 sc1" :: "v"(p), "v"(v32) : "memory");
}

// Decentralized flag barrier: per-block 4B flag (256B total, 2 cache lines).
// No central RMW; all 4 waves poll independently (one coalesced load covers
// all 64 flags), so there is no post-poll __syncthreads fan-out.
static __device__ __forceinline__ void wait_phase(const unsigned* flags, unsigned goal, int lane) {
  for (;;) {
    unsigned f = __hip_atomic_load(flags + lane, __ATOMIC_RELAXED, __HIP_MEMORY_SCOPE_AGENT);
    if (__all((int)(f >= goal))) return;
    __builtin_amdgcn_s_sleep(1);
  }
}

// Per-wave store drain -> block-wide join -> publish this block's phase seq.
// Data stores are ACKed at LLC (vmcnt(0)) before the flag store is even
// issued, so flag-visibility implies data-visibility for sc1 readers.
static __device__ __forceinline__ void drain_and_signal(unsigned* flags, int wg, int tid, unsigned seq) {
  asm volatile("s_waitcnt vmcnt(0)" ::: "memory");
  __syncthreads();
  if (tid == 0)
    asm volatile("global_store_dword %0, %1, off sc0 sc1" :: "v"(flags + wg), "v"(seq) : "memory");
}

// ---------------------------------------------------------------------------
// K0a: emb fp32 -> f16
__global__ void k_emb_convert(const float* __restrict__ src, f16* __restrict__ dst, int n4) {
  int i = blockIdx.x * 256 + threadIdx.x;
  if (i >= n4) return;
  float4 v = ((const float4*)src)[i];
  f16x4 o = {(f16)v.x, (f16)v.y, (f16)v.z, (f16)v.w};
  ((f16x4*)dst)[i] = o;
}

// K0b: pack bottom (x_emb) halves of W_z|W_r|W_h into B-fragment order:
// Bpk[ntile(192)][kstep(16)][lane(64)][j(8)]  (n = ntile*16 + lane&15, k = kstep*32 + quad*8 + j)
__global__ void k_pack_bot(const float* __restrict__ Wz, const float* __restrict__ Wr,
                           const float* __restrict__ Wh, f16* __restrict__ Bpk) {
  int tid = blockIdx.x * 256 + threadIdx.x;  // 196608
  int lane = tid & 63, kstep = (tid >> 6) & 15, ntile = tid >> 10;
  int n = ntile * 16 + (lane & 15);
  const float* W = (n < 1024) ? Wz : (n < 2048 ? Wr : Wh);
  int ncol = n & 1023;
  int kbase = kstep * 32 + (lane >> 4) * 8;
  f16x8 v;
#pragma unroll
  for (int j = 0; j < 8; ++j) v[j] = (f16)W[(size_t)(1024 + kbase + j) * 1024 + ncol];
  ((f16x8*)Bpk)[tid] = v;
}

// K0c: pack top (h) halves into per-block register-load order:
// Tpk[m(3)][wg(64)][kstep(32)][lane(64)][j(8)]  (col = wg*16 + lane&15, k = kstep*32 + quad*8 + j)
__global__ void k_pack_top(const float* __restrict__ Wz, const float* __restrict__ Wr,
                           const float* __restrict__ Wh, f16* __restrict__ Tpk) {
  int tid = blockIdx.x * 256 + threadIdx.x;  // 393216
  int lane = tid & 63, kstep = (tid >> 6) & 31, wg = (tid >> 11) & 63, m = tid >> 17;
  const float* W = (m == 0) ? Wz : (m == 1 ? Wr : Wh);
  int col = wg * 16 + (lane & 15);
  int kbase = kstep * 32 + (lane >> 4) * 8;
  f16x8 v;
#pragma unroll
  for (int j = 0; j < 8; ++j) v[j] = (f16)W[(size_t)(kbase + j) * 1024 + col];
  ((f16x8*)Tpk)[tid] = v;
}

// K0d: h0 fp32 -> f16, written directly in the fragment-split exchange layout.
__global__ void k_h_convert(const float* __restrict__ h0, f16* __restrict__ hfrag) {
  int i = blockIdx.x * 256 + threadIdx.x;  // 65536 f16 elements
  int slot = i & 3, ln = (i >> 2) & 63, wsel = (i >> 8) & 1, frag = i >> 9;
  int ks = frag & 31, mt = frag >> 5;
  int b = mt * 16 + (ln & 15);
  int k = ks * 32 + (ln >> 4) * 8 + wsel * 4 + slot;
  hfrag[i] = (f16)h0[(size_t)b * kDL + k];
}

// ---------------------------------------------------------------------------
// K1: X-projection GEMM with fused embedding gather.
// C[32768,3072] = gather(emb16, X)[32768,512] @ Bpk[512,3072]
// cols 0..2047 (z|r parts) -> Xzr (f16, stored INSIDE d_out), cols 2048.. -> Xh (ws)
__global__ __launch_bounds__(256, 2)
void k_xproj(const int* __restrict__ X, const f16* __restrict__ emb16,
             const f16* __restrict__ Bpk, f16* Xzr, f16* __restrict__ Xh) {
  const int bm = blockIdx.x / 24, bn = blockIdx.x % 24;
  const int tid = threadIdx.x;
  const int w = tid >> 6, lane = tid & 63, l15 = lane & 15, quad = lane >> 4;

  __shared__ int tok[128];
  __shared__ f16x8 Asm[8 * 2 * 64];  // [mtile][kstep][lane] fragment order
  __shared__ f16x8 Bsm[8 * 2 * 64];  // [ntile][kstep][lane]

  if (tid < 128) tok[tid] = X[bm * 128 + tid];
  __syncthreads();

  f32x4 zero4 = {0.f, 0.f, 0.f, 0.f};
  f32x4 acc[4][4];
#pragma unroll
  for (int i = 0; i < 4; ++i)
#pragma unroll
    for (int j = 0; j < 4; ++j) acc[i][j] = zero4;

  const int mtb = (w & 1) * 4, ntb = (w >> 1) * 4;

  for (int ki = 0; ki < 8; ++ki) {
    // stage A (gathered embedding rows), 128 rows x 64 k, fragment-ordered
#pragma unroll
    for (int c = 0; c < 4; ++c) {
      int cid = c * 256 + tid;
      int r = cid >> 3, kc = cid & 7;
      Asm[((r >> 4) * 2 + (kc >> 2)) * 64 + (kc & 3) * 16 + (r & 15)] =
          *(const f16x8*)(emb16 + (size_t)tok[r] * kDI + ki * 64 + kc * 8);
    }
    // stage B (prepacked, pure contiguous copy)
#pragma unroll
    for (int c = 0; c < 4; ++c) {
      int cid = c * 256 + tid;
      int nt = cid >> 7, ks = (cid >> 6) & 1, ln = cid & 63;
      Bsm[cid] = ((const f16x8*)Bpk)[((size_t)(bn * 8 + nt) * 16 + (ki * 2 + ks)) * 64 + ln];
    }
    __syncthreads();
#pragma unroll
    for (int ks = 0; ks < 2; ++ks) {
      f16x8 a[4], b[4];
#pragma unroll
      for (int i = 0; i < 4; ++i) a[i] = Asm[((mtb + i) * 2 + ks) * 64 + lane];
#pragma unroll
      for (int j = 0; j < 4; ++j) b[j] = Bsm[((ntb + j) * 2 + ks) * 64 + lane];
#pragma unroll
      for (int i = 0; i < 4; ++i)
#pragma unroll
        for (int j = 0; j < 4; ++j) acc[i][j] = MFMA16(a[i], b[j], acc[i][j]);
    }
    __syncthreads();
  }

  const int rowb = bm * 128 + (w & 1) * 64;
  const int colb = bn * 128 + (w >> 1) * 64;
#pragma unroll
  for (int i = 0; i < 4; ++i)
#pragma unroll
    for (int j = 0; j < 4; ++j)
#pragma unroll
      for (int reg = 0; reg < 4; ++reg) {
        int row = rowb + i * 16 + quad * 4 + reg;
        int col = colb + j * 16 + l15;
        f16 v = (f16)acc[i][j][reg];
        if (col < 2048) Xzr[(size_t)row * 2048 + col] = v;
        else            Xh[(size_t)row * 1024 + (col - 2048)] = v;
      }
}

// ---------------------------------------------------------------------------
// K2: persistent recurrent kernel. 64 blocks x 256 threads; block i owns cols
// [16i,16i+16) of z,r,cand,h. Recurrent weights in registers; h state fp32 in
// registers; f16 broadcast of h/rh through LLC in MFMA-fragment order; 2
// flag-waits per step (same ordering semantics as the old central barrier:
// a block enters phase P+1 only after ALL 64 blocks published phase P, which
// also protects the single-buffered hfrag/rhfrag WAR and the Xzr/H aliasing).
__global__ __launch_bounds__(256, 1)
void k_gru(const float* __restrict__ h0, const f16* __restrict__ Tpk,
           const f16* Xzr /* aliases H */, const f16* __restrict__ Xh,
           f16* hfrag, f16* rhfrag, unsigned* flags, float* H) {
  const int wg = blockIdx.x;
  const int tid = threadIdx.x;
  const int w = tid >> 6, lane = tid & 63, l15 = lane & 15, quad = lane >> 4;
  const int colbase = wg * 16;

  __shared__ f32x4 red[4][4][2][64];  // [src wave][mtile][z/r][lane] = 32 KB

  f32x4 zero4 = {0.f, 0.f, 0.f, 0.f};

  // Per-wave K-quarter weights -> registers (constant for all 512 steps): 96 VGPR/lane
  const f16x8* T = (const f16x8*)Tpk;
  f16x8 wz[8], wr[8], wh[8];
#pragma unroll
  for (int s = 0; s < 8; ++s) {
    int ks = w * 8 + s;
    wz[s] = T[((0 * 64 + wg) * 32 + ks) * 64 + lane];
    wr[s] = T[((1 * 64 + wg) * 32 + ks) * 64 + lane];
    wh[s] = T[((2 * 64 + wg) * 32 + ks) * 64 + lane];
  }

  // Persistent fp32 h state: lane owns h[b = w*16+quad*4+r4][colbase+l15]  (MFMA C/D layout)
  float hreg[4];
#pragma unroll
  for (int r4 = 0; r4 < 4; ++r4) {
    int b = w * 16 + quad * 4 + r4;
    hreg[r4] = h0[(size_t)b * kDL + colbase + l15];
  }

  // Scatter base (f16 units) into the fragment-split exchange layout; +4 per r4.
  //   value h[b][c], b = w*16+quad*4+r4, c = 16*wg+l15 lands at
  //   frag = w*32 + (wg>>1), plane = (l15>>2)&1,
  //   lane_dst = ((wg&1)*2 + (l15>>3))*16 + quad*4 + r4, slot = l15&3
  const int lane_dst0 = ((wg & 1) * 2 + (l15 >> 3)) * 16 + quad * 4;
  const int scat = ((w * 32 + (wg >> 1)) * 128 + ((l15 >> 2) & 1) * 64 + lane_dst0) * 4 + (l15 & 3);
  f16* const rh_p = rhfrag + scat;
  f16* const h_p  = hfrag  + scat;

  const unsigned long long* hq = (const unsigned long long*)hfrag;
  const unsigned long long* rq = (const unsigned long long*)rhfrag;

  unsigned seq = 0;

#pragma unroll 1
  for (int t = 0; t < kS; ++t) {
    // ---------- phase A: z,r partials over this wave's K-quarter ----------
    // Hoist independent x-projection loads: they fly during the flag wait.
    float xz[4], xr[4];
#pragma unroll
    for (int r4 = 0; r4 < 4; ++r4) {
      int b = w * 16 + quad * 4 + r4;
      size_t xi = ((size_t)t * kB + b) * 2048 + colbase + l15;
      xz[r4] = (float)Xzr[xi];
      xr[r4] = (float)Xzr[xi + 1024];
    }

    wait_phase(flags, seq, lane);  // h(t-1) published by all blocks (seq == 2t)

    // 64 fully-coalesced 8B sc1 loads in flight (two 512B planes/fragment).
    f16x8 af[8][4];
#pragma unroll
    for (int mt = 0; mt < 4; ++mt) {
      const unsigned long long* pm = hq + (size_t)(mt * 32 + w * 8) * 128 + lane;
#pragma unroll
      for (int s = 0; s < 8; ++s) {
        U128 u;
        u.q[0] = __hip_atomic_load(pm + s * 128,      __ATOMIC_RELAXED, __HIP_MEMORY_SCOPE_AGENT);
        u.q[1] = __hip_atomic_load(pm + s * 128 + 64, __ATOMIC_RELAXED, __HIP_MEMORY_SCOPE_AGENT);
        af[s][mt] = u.v;
      }
    }

    f32x4 az[4], ar[4];
#pragma unroll
    for (int mt = 0; mt < 4; ++mt) { az[mt] = zero4; ar[mt] = zero4; }
#pragma unroll
    for (int s = 0; s < 8; ++s)
#pragma unroll
      for (int mt = 0; mt < 4; ++mt) {
        az[mt] = MFMA16(af[s][mt], wz[s], az[mt]);
        ar[mt] = MFMA16(af[s][mt], wr[s], ar[mt]);
      }

#pragma unroll
    for (int mt = 0; mt < 4; ++mt) { red[w][mt][0][lane] = az[mt]; red[w][mt][1][lane] = ar[mt]; }
    __syncthreads();
    f32x4 zs = red[0][w][0][lane] + red[1][w][0][lane] + red[2][w][0][lane] + red[3][w][0][lane];
    f32x4 rs = red[0][w][1][lane] + red[1][w][1][lane] + red[2][w][1][lane] + red[3][w][1][lane];

    float zreg[4];
#pragma unroll
    for (int r4 = 0; r4 < 4; ++r4) {
      float zin = zs[r4] + xz[r4];
      float rin = rs[r4] + xr[r4];
      float z = 1.f / (1.f + __expf(-zin));
      float r = 1.f / (1.f + __expf(-rin));
      zreg[r4] = z;
      store_llc_f16(rh_p + r4 * 4, (f16)(r * hreg[r4]));
    }
    drain_and_signal(flags, wg, tid, ++seq);  // publish r*h  (seq == 2t+1)

    // ---------- phase B: candidate + state update ----------
    float xh[4];
#pragma unroll
    for (int r4 = 0; r4 < 4; ++r4) {
      int b = w * 16 + quad * 4 + r4;
      xh[r4] = (float)Xh[((size_t)t * kB + b) * kDL + colbase + l15];
    }

    wait_phase(flags, seq, lane);  // r*h published by all blocks

    f16x8 bf[8][4];
#pragma unroll
    for (int mt = 0; mt < 4; ++mt) {
      const unsigned long long* pm = rq + (size_t)(mt * 32 + w * 8) * 128 + lane;
#pragma unroll
      for (int s = 0; s < 8; ++s) {
        U128 u;
        u.q[0] = __hip_atomic_load(pm + s * 128,      __ATOMIC_RELAXED, __HIP_MEMORY_SCOPE_AGENT);
        u.q[1] = __hip_atomic_load(pm + s * 128 + 64, __ATOMIC_RELAXED, __HIP_MEMORY_SCOPE_AGENT);
        bf[s][mt] = u.v;
      }
    }

    f32x4 ac[4];
#pragma unroll
    for (int mt = 0; mt < 4; ++mt) ac[mt] = zero4;
#pragma unroll
    for (int s = 0; s < 8; ++s)
#pragma unroll
      for (int mt = 0; mt < 4; ++mt)
        ac[mt] = MFMA16(bf[s][mt], wh[s], ac[mt]);

#pragma unroll
    for (int mt = 0; mt < 4; ++mt) red[w][mt][0][lane] = ac[mt];
    __syncthreads();
    f32x4 cs = red[0][w][0][lane] + red[1][w][0][lane] + red[2][w][0][lane] + red[3][w][0][lane];

#pragma unroll
    for (int r4 = 0; r4 < 4; ++r4) {
      int b = w * 16 + quad * 4 + r4;
      float cin = cs[r4] + xh[r4];
      float cand = 1.f - 2.f / (__expf(2.f * cin) + 1.f);  // tanh
      float hn = hreg[r4] + zreg[r4] * (cand - hreg[r4]);
      hreg[r4] = hn;
      H[((size_t)t * kB + b) * kDL + colbase + l15] = hn;   // fp32 output (plain)
      store_llc_f16(h_p + r4 * 4, (f16)hn);                 // f16 broadcast copy
    }
    drain_and_signal(flags, wg, tid, ++seq);  // publish h(t)  (seq == 2t+2)
  }
}

// ---------------------------------------------------------------------------
extern "C" void kernel_launch(void* const* d_in, const int* in_sizes, int n_in,
                              void* d_out, int out_size, void* d_ws, size_t ws_size,
                              hipStream_t stream) {
  const int*   X   = (const int*)d_in[0];
  const float* h0  = (const float*)d_in[1];
  const float* emb = (const float*)d_in[2];
  const float* Wz  = (const float*)d_in[3];
  const float* Wr  = (const float*)d_in[4];
  const float* Wh  = (const float*)d_in[5];
  float* H = (float*)d_out;

  char* ws = (char*)d_ws;
  size_t o = 0;
  f16* emb16 = (f16*)(ws + o); o += (size_t)kV * kDI * 2;          // 51,463,168
  f16* Bpk   = (f16*)(ws + o); o += (size_t)3072 * 512 * 2;        //  3,145,728
  f16* Tpk   = (f16*)(ws + o); o += (size_t)3 * 1024 * 1024 * 2;   //  6,291,456
  f16* hfrag = (f16*)(ws + o); o += (size_t)kB * kDL * 2;          //    131,072
  f16* rhfrag= (f16*)(ws + o); o += (size_t)kB * kDL * 2;          //    131,072
  unsigned* flags = (unsigned*)(ws + o); o += 256;                 // 64 flags, 2 lines
  f16* Xh    = (f16*)(ws + o); o += (size_t)kS * kB * kDL * 2;     // 67,108,864
  // total ~128.3 MB of d_ws; z/r projections (f16, 134.2 MB) live inside d_out.
  f16* Xzr = (f16*)d_out;

  hipMemsetAsync(flags, 0, 256, stream);

  int n4 = kV * kDI / 4;
  k_emb_convert<<<(n4 + 255) / 256, 256, 0, stream>>>(emb, emb16, n4);
  k_pack_bot<<<196608 / 256, 256, 0, stream>>>(Wz, Wr, Wh, Bpk);
  k_pack_top<<<393216 / 256, 256, 0, stream>>>(Wz, Wr, Wh, Tpk);
  k_h_convert<<<65536 / 256, 256, 0, stream>>>(h0, hfrag);
  k_xproj<<<256 * 24, 256, 0, stream>>>(X, emb16, Bpk, Xzr, Xh);
  k_gru<<<64, 256, 0, stream>>>(h0, Tpk, Xzr, Xh, hfrag, rhfrag, flags, H);
}